// Round 4
// baseline (260.214 us; speedup 1.0000x reference)
//
#include <hip/hip_runtime.h>

// EdgeModel: out = relu(x@W1+b1)@W2 + b2 + x, x = [src|dest|ea|u[batch]].
// E=1e6, dims 128. bf16 MFMA 16x16x32, fp32 accum.
// R4: BOTH GEMMs transposed (C rows = hidden/out-dim, cols = edges):
//   h^T = W1^T x^T          -> h->LDS as b64 writes
//   out^T = W2^T h^T + I x^T -> epilogue is 8 nontemporal dwordx4 stores/thread
// 2 barriers/tile, grid 2048 (R2 value), prefetch 1 tile ahead.

#define E_TOTAL   1000000
#define TILE_M    64
#define NUM_TILES (E_TOTAL / TILE_M)   // 15625
#define GRID      2048

typedef __attribute__((ext_vector_type(8))) __bf16 bf16x8;
typedef __attribute__((ext_vector_type(4))) __bf16 bf16x4;
typedef __attribute__((ext_vector_type(4))) float  f32x4;

__device__ inline bf16x8 pack8(f32x4 v0, f32x4 v1) {
    bf16x8 r;
    r[0] = (__bf16)v0[0]; r[1] = (__bf16)v0[1];
    r[2] = (__bf16)v0[2]; r[3] = (__bf16)v0[3];
    r[4] = (__bf16)v1[0]; r[5] = (__bf16)v1[1];
    r[6] = (__bf16)v1[2]; r[7] = (__bf16)v1[3];
    return r;
}

// row-major [64][128] bf16, 16 groups of 8/row, group XOR (row&15):
// all b128 reads conflict-free.
__device__ inline int swz(int row, int group) {
    return (row * 16 + (group ^ (row & 15))) * 8;
}

__global__ __launch_bounds__(256, 2)
void edge_mlp(const float* __restrict__ gsrc,
              const float* __restrict__ gdst,
              const float* __restrict__ gea,
              const float* __restrict__ gu,
              const int*   __restrict__ gbatch,
              const float* __restrict__ gw1,
              const float* __restrict__ gb1,
              const float* __restrict__ gw2,
              const float* __restrict__ gb2,
              float* __restrict__ gout)
{
    __shared__ __align__(16) __bf16 xs[TILE_M * 128];   // x tile (bf16, swizzled)
    __shared__ __align__(16) __bf16 hl[TILE_M * 128];   // h tile (bf16, swizzled)

    const int tid  = threadIdx.x;
    const int lane = tid & 63;
    const int wid  = tid >> 6;     // wave owns hidden rows / out-dim rows [wb,wb+32)
    const int l15  = lane & 15;
    const int g    = lane >> 4;
    const int wb   = wid * 32;

    // ---- W1^T and W2^T as A-fragments:
    //      lane holds W^T[row = wb+m*16+l15][k = ks*32+g*8+j] = gw[k*128+row]
    bf16x8 w1t[2][4], w2t[2][4];
#pragma unroll
    for (int m = 0; m < 2; ++m)
#pragma unroll
        for (int ks = 0; ks < 4; ++ks) {
            bf16x8 t1, t2;
#pragma unroll
            for (int j = 0; j < 8; ++j) {
                const int k = ks * 32 + g * 8 + j;
                const int r = wb + m * 16 + l15;
                t1[j] = (__bf16)gw1[k * 128 + r];
                t2[j] = (__bf16)gw2[k * 128 + r];
            }
            w1t[m][ks] = t1;
            w2t[m][ks] = t2;
        }

    // ---- identity A-fragments for residual I@x^T (nonzero k-slice: ks==wid)
    //      A[row=wb+m*16+l15][k=wid*32+g*8+j] = 1 iff g*8+j == m*16+l15
    bf16x8 idf[2];
#pragma unroll
    for (int m = 0; m < 2; ++m) {
        bf16x8 t;
#pragma unroll
        for (int j = 0; j < 8; ++j)
            t[j] = (8 * g + j == 16 * m + l15) ? (__bf16)1.0f : (__bf16)0.0f;
        idf[m] = t;
    }

    // ---- biases along C rows: b[wb + m*16 + g*4 + r]
    f32x4 b1v[2], b2v[2];
#pragma unroll
    for (int m = 0; m < 2; ++m)
#pragma unroll
        for (int r = 0; r < 4; ++r) {
            b1v[m][r] = gb1[wb + m * 16 + g * 4 + r];
            b2v[m][r] = gb2[wb + m * 16 + g * 4 + r];
        }

    // ---- staging: thread t owns edge-row t>>2, 8-float chunk t&3 ----
    const int srow = tid >> 2;
    const int ssub = tid & 3;

    f32x4 pre[4][2];
    auto load_pre = [&](int t) {
        const int e = t * TILE_M + srow;
        const int bi = gbatch[e];          // first: gates the u gather
        const float* p0 = gsrc + (size_t)e * 32 + ssub * 8;
        const float* p1 = gdst + (size_t)e * 32 + ssub * 8;
        const float* p2 = gea  + (size_t)e * 32 + ssub * 8;
        pre[0][0] = *(const f32x4*)p0; pre[0][1] = *(const f32x4*)(p0 + 4);
        pre[1][0] = *(const f32x4*)p1; pre[1][1] = *(const f32x4*)(p1 + 4);
        pre[2][0] = *(const f32x4*)p2; pre[2][1] = *(const f32x4*)(p2 + 4);
        const float* p3 = gu + (size_t)bi * 32 + ssub * 8;
        pre[3][0] = *(const f32x4*)p3; pre[3][1] = *(const f32x4*)(p3 + 4);
    };

    int tile = blockIdx.x;
    load_pre(tile);

    while (true) {
        // ---- stage x tile into LDS (bf16, swizzled) ----
#pragma unroll
        for (int p = 0; p < 4; ++p)
            *(bf16x8*)&xs[swz(srow, p * 4 + ssub)] = pack8(pre[p][0], pre[p][1]);
        __syncthreads();                                   // bar1

        const int  nxt  = tile + GRID;
        const bool have = nxt < NUM_TILES;
        if (have) load_pre(nxt);

        // ---- GEMM1^T: h^T = W1^T @ x^T + b1 ----
        f32x4 acc[2][4];
#pragma unroll
        for (int m = 0; m < 2; ++m)
#pragma unroll
            for (int n = 0; n < 4; ++n)
                acc[m][n] = b1v[m];
#pragma unroll
        for (int ks = 0; ks < 4; ++ks) {
            bf16x8 bf[4];
#pragma unroll
            for (int n = 0; n < 4; ++n)
                bf[n] = *(const bf16x8*)&xs[swz(n * 16 + l15, ks * 4 + g)];
#pragma unroll
            for (int m = 0; m < 2; ++m)
#pragma unroll
                for (int n = 0; n < 4; ++n)
                    acc[m][n] = __builtin_amdgcn_mfma_f32_16x16x32_bf16(
                        w1t[m][ks], bf[n], acc[m][n], 0, 0, 0);
        }

        // ---- residual B-fragments: x^T k-slice [wb, wb+32) ----
        bf16x8 aid[4];
#pragma unroll
        for (int n = 0; n < 4; ++n)
            aid[n] = *(const bf16x8*)&xs[swz(n * 16 + l15, wid * 4 + g)];

        // ---- ReLU + pack + h -> LDS (b64: 4 consecutive hidden dims) ----
#pragma unroll
        for (int m = 0; m < 2; ++m)
#pragma unroll
            for (int n = 0; n < 4; ++n) {
                f32x4 v = acc[m][n];
                bf16x4 h4;
#pragma unroll
                for (int r = 0; r < 4; ++r) {
                    float x = v[r];
                    h4[r] = (__bf16)(x > 0.f ? x : 0.f);
                }
                const int hid = wb + m * 16 + 4 * g;       // 4-aligned
                *(bf16x4*)&hl[swz(n * 16 + l15, hid >> 3) + (hid & 7)] = h4;
            }

        // ---- start out^T accumulators: bias + residual (uses xs, pre-bar2) ----
        f32x4 acc2[2][4];
#pragma unroll
        for (int m = 0; m < 2; ++m)
#pragma unroll
            for (int n = 0; n < 4; ++n)
                acc2[m][n] = __builtin_amdgcn_mfma_f32_16x16x32_bf16(
                    idf[m], aid[n], b2v[m], 0, 0, 0);
        __syncthreads();                                   // bar2

        // ---- GEMM2^T: out^T += W2^T @ h^T ----
#pragma unroll
        for (int ks = 0; ks < 4; ++ks) {
            bf16x8 bh[4];
#pragma unroll
            for (int n = 0; n < 4; ++n)
                bh[n] = *(const bf16x8*)&hl[swz(n * 16 + l15, ks * 4 + g)];
#pragma unroll
            for (int m = 0; m < 2; ++m)
#pragma unroll
                for (int n = 0; n < 4; ++n)
                    acc2[m][n] = __builtin_amdgcn_mfma_f32_16x16x32_bf16(
                        w2t[m][ks], bh[n], acc2[m][n], 0, 0, 0);
        }

        // ---- epilogue: nontemporal float4 stores (4 consecutive out dims) ----
        const int e0 = tile * TILE_M;
#pragma unroll
        for (int n = 0; n < 4; ++n) {
            const size_t rowbase = (size_t)(e0 + n * 16 + l15) * 128;
#pragma unroll
            for (int m = 0; m < 2; ++m)
                __builtin_nontemporal_store(
                    acc2[m][n],
                    (f32x4*)&gout[rowbase + wb + m * 16 + g * 4]);
        }

        if (!have) break;
        tile = nxt;
    }
}

extern "C" void kernel_launch(void* const* d_in, const int* in_sizes, int n_in,
                              void* d_out, int out_size, void* d_ws, size_t ws_size,
                              hipStream_t stream) {
    const float* src = (const float*)d_in[0];
    const float* dst = (const float*)d_in[1];
    const float* ea  = (const float*)d_in[2];
    const float* u   = (const float*)d_in[3];
    const int*   bt  = (const int*)d_in[4];
    const float* w1  = (const float*)d_in[5];
    const float* b1  = (const float*)d_in[6];
    const float* w2  = (const float*)d_in[7];
    const float* b2  = (const float*)d_in[8];
    float* out = (float*)d_out;

    edge_mlp<<<GRID, 256, 0, stream>>>(src, dst, ea, u, bt, w1, b1, w2, b2, out);
}

// Round 5
// 177.474 us; speedup vs baseline: 1.4662x; 1.4662x over previous
//
#include <hip/hip_runtime.h>

// EdgeModel: out = relu(x@W1+b1)@W2 + b2 + x, x = [src|dest|ea|u[batch]].
// E=1e6, dims 128. bf16 MFMA 16x16x32, fp32 accum.
// R5: R4 structure (both GEMMs transposed; h->LDS b64; residual as identity
// MFMA; 2 barriers/tile; dwordx4 epilogue) but PLAIN stores (nt caused 1.44x
// write amplification: L2 evicted partial 128B lines before write-combining).

#define E_TOTAL   1000000
#define TILE_M    64
#define NUM_TILES (E_TOTAL / TILE_M)   // 15625
#define GRID      2048

typedef __attribute__((ext_vector_type(8))) __bf16 bf16x8;
typedef __attribute__((ext_vector_type(4))) __bf16 bf16x4;
typedef __attribute__((ext_vector_type(4))) float  f32x4;

__device__ inline bf16x8 pack8(f32x4 v0, f32x4 v1) {
    bf16x8 r;
    r[0] = (__bf16)v0[0]; r[1] = (__bf16)v0[1];
    r[2] = (__bf16)v0[2]; r[3] = (__bf16)v0[3];
    r[4] = (__bf16)v1[0]; r[5] = (__bf16)v1[1];
    r[6] = (__bf16)v1[2]; r[7] = (__bf16)v1[3];
    return r;
}

// row-major [64][128] bf16, 16 groups of 8/row, group XOR (row&15):
// all b128 reads conflict-free.
__device__ inline int swz(int row, int group) {
    return (row * 16 + (group ^ (row & 15))) * 8;
}

__global__ __launch_bounds__(256, 2)
void edge_mlp(const float* __restrict__ gsrc,
              const float* __restrict__ gdst,
              const float* __restrict__ gea,
              const float* __restrict__ gu,
              const int*   __restrict__ gbatch,
              const float* __restrict__ gw1,
              const float* __restrict__ gb1,
              const float* __restrict__ gw2,
              const float* __restrict__ gb2,
              float* __restrict__ gout)
{
    __shared__ __align__(16) __bf16 xs[TILE_M * 128];   // x tile (bf16, swizzled)
    __shared__ __align__(16) __bf16 hl[TILE_M * 128];   // h tile (bf16, swizzled)

    const int tid  = threadIdx.x;
    const int lane = tid & 63;
    const int wid  = tid >> 6;     // wave owns hidden/out-dim rows [wb,wb+32)
    const int l15  = lane & 15;
    const int g    = lane >> 4;
    const int wb   = wid * 32;

    // ---- W1^T and W2^T as A-fragments:
    //      lane holds W^T[row = wb+m*16+l15][k = ks*32+g*8+j] = gw[k*128+row]
    bf16x8 w1t[2][4], w2t[2][4];
#pragma unroll
    for (int m = 0; m < 2; ++m)
#pragma unroll
        for (int ks = 0; ks < 4; ++ks) {
            bf16x8 t1, t2;
#pragma unroll
            for (int j = 0; j < 8; ++j) {
                const int k = ks * 32 + g * 8 + j;
                const int r = wb + m * 16 + l15;
                t1[j] = (__bf16)gw1[k * 128 + r];
                t2[j] = (__bf16)gw2[k * 128 + r];
            }
            w1t[m][ks] = t1;
            w2t[m][ks] = t2;
        }

    // ---- identity A-fragments for residual I@x^T (nonzero k-slice: ks==wid)
    bf16x8 idf[2];
#pragma unroll
    for (int m = 0; m < 2; ++m) {
        bf16x8 t;
#pragma unroll
        for (int j = 0; j < 8; ++j)
            t[j] = (8 * g + j == 16 * m + l15) ? (__bf16)1.0f : (__bf16)0.0f;
        idf[m] = t;
    }

    // ---- biases along C rows: b[wb + m*16 + g*4 + r]
    f32x4 b1v[2], b2v[2];
#pragma unroll
    for (int m = 0; m < 2; ++m)
#pragma unroll
        for (int r = 0; r < 4; ++r) {
            b1v[m][r] = gb1[wb + m * 16 + g * 4 + r];
            b2v[m][r] = gb2[wb + m * 16 + g * 4 + r];
        }

    // ---- staging: thread t owns edge-row t>>2, 8-float chunk t&3 ----
    const int srow = tid >> 2;
    const int ssub = tid & 3;

    f32x4 pre[4][2];
    auto load_pre = [&](int t) {
        const int e = t * TILE_M + srow;
        const int bi = gbatch[e];          // first: gates the u gather
        const float* p0 = gsrc + (size_t)e * 32 + ssub * 8;
        const float* p1 = gdst + (size_t)e * 32 + ssub * 8;
        const float* p2 = gea  + (size_t)e * 32 + ssub * 8;
        pre[0][0] = *(const f32x4*)p0; pre[0][1] = *(const f32x4*)(p0 + 4);
        pre[1][0] = *(const f32x4*)p1; pre[1][1] = *(const f32x4*)(p1 + 4);
        pre[2][0] = *(const f32x4*)p2; pre[2][1] = *(const f32x4*)(p2 + 4);
        const float* p3 = gu + (size_t)bi * 32 + ssub * 8;
        pre[3][0] = *(const f32x4*)p3; pre[3][1] = *(const f32x4*)(p3 + 4);
    };

    int tile = blockIdx.x;
    load_pre(tile);

    while (true) {
        // ---- stage x tile into LDS (bf16, swizzled) ----
#pragma unroll
        for (int p = 0; p < 4; ++p)
            *(bf16x8*)&xs[swz(srow, p * 4 + ssub)] = pack8(pre[p][0], pre[p][1]);
        __syncthreads();                                   // bar1

        const int  nxt  = tile + GRID;
        const bool have = nxt < NUM_TILES;
        if (have) load_pre(nxt);

        // ---- GEMM1^T: h^T = W1^T @ x^T + b1 ----
        f32x4 acc[2][4];
#pragma unroll
        for (int m = 0; m < 2; ++m)
#pragma unroll
            for (int n = 0; n < 4; ++n)
                acc[m][n] = b1v[m];
#pragma unroll
        for (int ks = 0; ks < 4; ++ks) {
            bf16x8 bf[4];
#pragma unroll
            for (int n = 0; n < 4; ++n)
                bf[n] = *(const bf16x8*)&xs[swz(n * 16 + l15, ks * 4 + g)];
#pragma unroll
            for (int m = 0; m < 2; ++m)
#pragma unroll
                for (int n = 0; n < 4; ++n)
                    acc[m][n] = __builtin_amdgcn_mfma_f32_16x16x32_bf16(
                        w1t[m][ks], bf[n], acc[m][n], 0, 0, 0);
        }

        // ---- residual B-fragments: x^T k-slice [wb, wb+32) ----
        bf16x8 aid[4];
#pragma unroll
        for (int n = 0; n < 4; ++n)
            aid[n] = *(const bf16x8*)&xs[swz(n * 16 + l15, wid * 4 + g)];

        // ---- ReLU + pack + h -> LDS (b64: 4 consecutive hidden dims) ----
#pragma unroll
        for (int m = 0; m < 2; ++m)
#pragma unroll
            for (int n = 0; n < 4; ++n) {
                f32x4 v = acc[m][n];
                bf16x4 h4;
#pragma unroll
                for (int r = 0; r < 4; ++r) {
                    float x = v[r];
                    h4[r] = (__bf16)(x > 0.f ? x : 0.f);
                }
                const int hid = wb + m * 16 + 4 * g;       // 4-aligned
                *(bf16x4*)&hl[swz(n * 16 + l15, hid >> 3) + (hid & 7)] = h4;
            }

        // ---- start out^T accumulators: bias + residual (uses xs, pre-bar2) ----
        f32x4 acc2[2][4];
#pragma unroll
        for (int m = 0; m < 2; ++m)
#pragma unroll
            for (int n = 0; n < 4; ++n)
                acc2[m][n] = __builtin_amdgcn_mfma_f32_16x16x32_bf16(
                    idf[m], aid[n], b2v[m], 0, 0, 0);
        __syncthreads();                                   // bar2

        // ---- GEMM2^T: out^T += W2^T @ h^T ----
#pragma unroll
        for (int ks = 0; ks < 4; ++ks) {
            bf16x8 bh[4];
#pragma unroll
            for (int n = 0; n < 4; ++n)
                bh[n] = *(const bf16x8*)&hl[swz(n * 16 + l15, ks * 4 + g)];
#pragma unroll
            for (int m = 0; m < 2; ++m)
#pragma unroll
                for (int n = 0; n < 4; ++n)
                    acc2[m][n] = __builtin_amdgcn_mfma_f32_16x16x32_bf16(
                        w2t[m][ks], bh[n], acc2[m][n], 0, 0, 0);
        }

        // ---- epilogue: plain float4 stores (4 consecutive out dims) ----
        // per row, this wave's m=0/m=1 pair covers cols [wb,wb+32) = one full
        // aligned 128B line -> L2 write-combines cleanly.
        const int e0 = tile * TILE_M;
#pragma unroll
        for (int n = 0; n < 4; ++n) {
            const size_t rowbase = (size_t)(e0 + n * 16 + l15) * 128;
#pragma unroll
            for (int m = 0; m < 2; ++m)
                *(f32x4*)&gout[rowbase + wb + m * 16 + g * 4] = acc2[m][n];
        }

        if (!have) break;
        tile = nxt;
    }
}

extern "C" void kernel_launch(void* const* d_in, const int* in_sizes, int n_in,
                              void* d_out, int out_size, void* d_ws, size_t ws_size,
                              hipStream_t stream) {
    const float* src = (const float*)d_in[0];
    const float* dst = (const float*)d_in[1];
    const float* ea  = (const float*)d_in[2];
    const float* u   = (const float*)d_in[3];
    const int*   bt  = (const int*)d_in[4];
    const float* w1  = (const float*)d_in[5];
    const float* b1  = (const float*)d_in[6];
    const float* w2  = (const float*)d_in[7];
    const float* b2  = (const float*)d_in[8];
    float* out = (float*)d_out;

    edge_mlp<<<GRID, 256, 0, stream>>>(src, dst, ea, u, bt, w1, b1, w2, b2, out);
}